// Round 7
// baseline (7618.575 us; speedup 1.0000x reference)
//
#include <hip/hip_runtime.h>
#include <stdint.h>
#include <stddef.h>

typedef unsigned short u16;

__device__ __forceinline__ float bf2f(u16 h) {
  union { unsigned u; float f; } v; v.u = ((unsigned)h) << 16; return v.f;
}
__device__ __forceinline__ u16 f2bf(float f) {
  union { float f; unsigned u; } v; v.f = f;
  return (u16)((v.u + 0x7FFFu + ((v.u >> 16) & 1u)) >> 16);
}
// Load element i of a tensor that is fp32 (f=1) or bf16 (f=0).
__device__ __forceinline__ float ldx(const void* p, size_t i, int f) {
  return f ? ((const float*)p)[i] : bf2f(((const u16*)p)[i]);
}

// Block-local dtype detect: scan first scan_n u16 for bf16 NaN/inf exponent
// (bits 14:7 all ones). Random fp32 hits ~1/256 of low halves; normal bf16
// never does. Returns 1 (fp32) / 0 (bf16), uniform across the block.
__device__ __forceinline__ int detect_fp32(const void* p, int scan_n, int* slot) {
  __syncthreads();
  if (threadIdx.x == 0) *slot = 0;
  __syncthreads();
  const u16* q = (const u16*)p;
  int c = 0;
  for (int i = threadIdx.x; i < scan_n; i += 256)
    c |= (((q[i] >> 7) & 0xFF) == 0xFF) ? 1 : 0;
  if (c) atomicOr(slot, 1);
  __syncthreads();
  return *slot;
}

// ---------------------------------------------------------------------------
// Naive tiled fp32 GEMM (vector ALU): C = A[M][K] @ W[K][N] + bias.
// Output column-split: n < split -> C0 (ld0), else C1 at n-split (ld1).
// out32: 1 -> write fp32, 0 -> write bf16.
// 64x64 tile, BK=16, 256 threads, 4x4 outputs/thread. In-dtypes self-detected.
// ---------------------------------------------------------------------------
__global__ __launch_bounds__(256) void gemm_naive_kernel(
    const void* __restrict__ A, const void* __restrict__ W,
    const void* __restrict__ bias, void* __restrict__ C0, void* __restrict__ C1,
    int M, int N, int K, int split, int ld0, int ld1,
    int scanA, int scanW, int scanBias, int out32) {
  __shared__ float As[16][65];  // [k][m]
  __shared__ float Ws[16][65];  // [k][n]
  __shared__ int s_hit;
  const int fa = detect_fp32(A, scanA, &s_hit);
  const int fw = detect_fp32(W, scanW, &s_hit);
  const int fb = detect_fp32(bias, scanBias, &s_hit);
  const int tid = threadIdx.x;
  const int tx = tid & 15, ty = tid >> 4;
  const int m0 = blockIdx.y * 64, n0 = blockIdx.x * 64;

  float acc[4][4] = {};

  for (int k0 = 0; k0 < K; k0 += 16) {
    __syncthreads();
    {
      const int kk = tid & 15, mlb = tid >> 4;
#pragma unroll
      for (int i = 0; i < 4; i++)
        As[kk][mlb + 16 * i] = ldx(A, (size_t)(m0 + mlb + 16 * i) * K + k0 + kk, fa);
      const int nl = tid & 63, kb = tid >> 6;
#pragma unroll
      for (int i = 0; i < 4; i++)
        Ws[kb + 4 * i][nl] = ldx(W, (size_t)(k0 + kb + 4 * i) * N + n0 + nl, fw);
    }
    __syncthreads();
#pragma unroll
    for (int kk = 0; kk < 16; kk++) {
      float a[4], b[4];
#pragma unroll
      for (int i = 0; i < 4; i++) a[i] = As[kk][ty + 16 * i];
#pragma unroll
      for (int j = 0; j < 4; j++) b[j] = Ws[kk][tx + 16 * j];
#pragma unroll
      for (int i = 0; i < 4; i++)
#pragma unroll
        for (int j = 0; j < 4; j++) acc[i][j] += a[i] * b[j];
    }
  }

#pragma unroll
  for (int j = 0; j < 4; j++) {
    const int n = n0 + tx + 16 * j;
    const float bv = ldx(bias, n, fb);
#pragma unroll
    for (int i = 0; i < 4; i++) {
      const int m = m0 + ty + 16 * i;
      const float val = acc[i][j] + bv;
      void* dst = (n < split) ? C0 : C1;
      const size_t idx = (n < split) ? (size_t)m * ld0 + n
                                     : (size_t)m * ld1 + (n - split);
      if (out32) ((float*)dst)[idx] = val;
      else       ((u16*)dst)[idx] = f2bf(val);
    }
  }
}

// ---------------------------------------------------------------------------
// Naive causal attention: one block per (query row, b*16+h). Full softmax in
// LDS. qbuf bf16 [8192][1024]; kv bf16 [8192][2048] (k cols 0..1023,
// v cols 1024..2047). Mask added (dtype self-detected; zeros anyway).
// ---------------------------------------------------------------------------
__global__ __launch_bounds__(256) void attn_naive_kernel(
    const u16* __restrict__ qbuf, const u16* __restrict__ kv,
    const void* __restrict__ am, int scanAm, u16* __restrict__ abuf) {
  __shared__ float q[64];
  __shared__ float sc[2048];
  __shared__ float red[256];
  __shared__ int s_hit;
  const int fm = detect_fp32(am, scanAm, &s_hit);
  const int tid = threadIdx.x;
  const int qrow = blockIdx.x;
  const int bh = blockIdx.y, b = bh >> 4, h = bh & 15;
  const size_t rowbase = (size_t)b * 2048;

  if (tid < 64) q[tid] = bf2f(qbuf[(rowbase + qrow) * 1024 + h * 64 + tid]);
  __syncthreads();

  const int nk = qrow + 1;  // masked keys contribute exp(-10000-m)=0 exactly
  for (int key = tid; key < nk; key += 256) {
    const u16* kp = kv + (rowbase + key) * 2048 + h * 64;
    float d = 0.f;
    for (int j = 0; j < 64; j++) d += q[j] * bf2f(kp[j]);
    sc[key] = d * 0.125f + ldx(am, (size_t)b * 2048 + key, fm);
  }
  __syncthreads();

  float lm = -1e30f;
  for (int key = tid; key < nk; key += 256) lm = fmaxf(lm, sc[key]);
  red[tid] = lm;
  __syncthreads();
  for (int s = 128; s > 0; s >>= 1) {
    if (tid < s) red[tid] = fmaxf(red[tid], red[tid + s]);
    __syncthreads();
  }
  const float m = red[0];
  __syncthreads();

  float ls = 0.f;
  for (int key = tid; key < nk; key += 256) {
    const float e = __expf(sc[key] - m);
    sc[key] = e;
    ls += e;
  }
  red[tid] = ls;
  __syncthreads();
  for (int s = 128; s > 0; s >>= 1) {
    if (tid < s) red[tid] += red[tid + s];
    __syncthreads();
  }
  const float l = red[0];
  __syncthreads();

  const int d = tid & 63, part = tid >> 6;
  float o = 0.f;
  for (int key = part; key < nk; key += 4)
    o += sc[key] * bf2f(kv[(rowbase + key) * 2048 + 1024 + h * 64 + d]);
  red[tid] = o;
  __syncthreads();
  if (tid < 64) {
    const float val = (red[tid] + red[tid + 64] + red[tid + 128] + red[tid + 192]) / l;
    abuf[(rowbase + qrow) * 1024 + h * 64 + tid] = f2bf(val);
  }
}

// ---------------------------------------------------------------------------
extern "C" void kernel_launch(void* const* d_in, const int* in_sizes, int n_in,
                              void* d_out, int out_size, void* d_ws, size_t ws_size,
                              hipStream_t stream) {
  (void)out_size; (void)ws_size;
  // Identify tensors by element count (all six unique). Fallback: dict order.
  auto find = [&](int count, int def_idx) -> const void* {
    for (int i = 0; i < n_in; i++)
      if (in_sizes[i] == count) return d_in[i];
    return d_in[def_idx];
  };
  const void* x  = find(8388608, 0);  // (4,2048,1024)
  const void* am = find(8192, 1);     // (4,1,1,2048)
  const void* Wa = find(3145728, 2);  // (1024,3072)
  const void* ba = find(3072, 3);     // (3072,)
  const void* Wp = find(1048576, 4);  // (1024,1024)
  const void* bp = find(1024, 5);     // (1024,)

  // Workspace (~67.1 MB; R3 demonstrated >=92 MB usable).
  char* ws = (char*)d_ws;
  u16* kv   = (u16*)(ws + 0);          // 8192*2048*2 = 33,554,432
  u16* abuf = (u16*)(ws + 33554432);   // 8192*1024*2 = 16,777,216
  u16* qbuf = (u16*)(ws + 50331648);   // 8192*1024*2 = 16,777,216

  const int M = 8192, D = 1024;

  // GEMM1: x @ Wa + ba -> bf16: cols<1024 to qbuf (ld 1024), rest to kv (ld 2048)
  gemm_naive_kernel<<<dim3(3072 / 64, M / 64), 256, 0, stream>>>(
      x, Wa, ba, qbuf, kv, M, 3072, D, 1024, 1024, 2048,
      4096, 4096, 3072, 0);
  attn_naive_kernel<<<dim3(2048, 64), 256, 0, stream>>>(qbuf, kv, am, 4096, abuf);
  // GEMM2: abuf @ Wp + bp -> d_out as FP32 (the round's single variable).
  gemm_naive_kernel<<<dim3(D / 64, M / 64), 256, 0, stream>>>(
      abuf, Wp, bp, d_out, d_out, M, D, D, D, D, D,
      0, 4096, 1024, 1);
}

// Round 8
// 512.527 us; speedup vs baseline: 14.8647x; 14.8647x over previous
//
#include <hip/hip_runtime.h>
#include <stdint.h>
#include <stddef.h>

typedef unsigned short u16;
typedef __attribute__((ext_vector_type(8))) short short8;   // 8 x bf16 MFMA A/B frag
typedef __attribute__((ext_vector_type(4))) float float4v;  // MFMA C/D frag

__device__ __forceinline__ float bf2f(u16 h) {
  union { unsigned u; float f; } v; v.u = ((unsigned)h) << 16; return v.f;
}
__device__ __forceinline__ u16 f2bf(float f) {
  union { float f; unsigned u; } v; v.f = f;
  return (u16)((v.u + 0x7FFFu + ((v.u >> 16) & 1u)) >> 16);
}

// ---------------------------------------------------------------------------
// Dtype detector (kept for robustness): bf16 NaN/inf exponent pattern scan.
// flag=1 -> fp32 (expected), flag=0 -> bf16.
// ---------------------------------------------------------------------------
__global__ __launch_bounds__(256) void detect_kernel(const u16* __restrict__ src,
                                                     int* __restrict__ flag) {
  __shared__ int cnt[256];
  int c = 0;
  for (int j = 0; j < 256; j++) {
    const u16 w = src[threadIdx.x + j * 256];
    c += (((w >> 7) & 0xFF) == 0xFF) ? 1 : 0;
  }
  cnt[threadIdx.x] = c;
  __syncthreads();
  if (threadIdx.x == 0) {
    int t = 0;
    for (int i = 0; i < 256; i++) t += cnt[i];
    *flag = (t > 0) ? 1 : 0;
  }
}

// Elementwise convert to bf16. flag=1: src fp32; flag=0: src bf16.
__global__ __launch_bounds__(256) void cvt_bf16_kernel(const void* __restrict__ src,
                                                       const int* __restrict__ flag,
                                                       u16* __restrict__ dst, int n) {
  const int f = *flag;
  const int stride = gridDim.x * 256;
  for (int i = blockIdx.x * 256 + threadIdx.x; i < n; i += stride)
    dst[i] = f ? f2bf(((const float*)src)[i]) : ((const u16*)src)[i];
}

// Elementwise convert to fp32.
__global__ __launch_bounds__(256) void cvt_f32_kernel(const void* __restrict__ src,
                                                      const int* __restrict__ flag,
                                                      float* __restrict__ dst, int n) {
  const int f = *flag;
  const int stride = gridDim.x * 256;
  for (int i = blockIdx.x * 256 + threadIdx.x; i < n; i += stride)
    dst[i] = f ? ((const float*)src)[i] : bf2f(((const u16*)src)[i]);
}

// Fused convert + transpose: src [R][C] -> dst [C][R] bf16. R,C mult of 64.
__global__ __launch_bounds__(256) void cvt_transpose_kernel(
    const void* __restrict__ src, const int* __restrict__ flag,
    u16* __restrict__ dst, int R, int C) {
  __shared__ u16 tile[64][65];
  const int f = *flag;
  const int c0 = blockIdx.x * 64, r0 = blockIdx.y * 64;
  const int tc = threadIdx.x & 63;
  const int tr0 = (threadIdx.x >> 6) * 16;
#pragma unroll
  for (int i = 0; i < 16; i++) {
    const size_t idx = (size_t)(r0 + tr0 + i) * C + c0 + tc;
    tile[tr0 + i][tc] = f ? f2bf(((const float*)src)[idx]) : ((const u16*)src)[idx];
  }
  __syncthreads();
#pragma unroll
  for (int i = 0; i < 16; i++)
    dst[(size_t)(c0 + tr0 + i) * R + r0 + tc] = tile[tc][tr0 + i];
}

// ---------------------------------------------------------------------------
// C[M][N] = A[M][K] @ Bt[N][K]^T + bias[N]   (bf16 in, fp32 accum)
// out32=1 -> fp32 C, out32=0 -> bf16 C.
// 128x128 tile, BK=64, 4 waves (2x2), each wave 64x64 = 4x4 MFMA 16x16x32.
// Plain staging via padded LDS (LD=72 u16 = 144 B).
// ---------------------------------------------------------------------------
__global__ __launch_bounds__(256) void gemm_bt_kernel(
    const u16* __restrict__ A, const u16* __restrict__ Bt,
    const float* __restrict__ bias, void* __restrict__ C,
    int M, int N, int K, int out32) {
  __shared__ __align__(16) u16 As[128 * 72];
  __shared__ __align__(16) u16 Bs[128 * 72];
  const int tid = threadIdx.x;
  const int wave = tid >> 6, lane = tid & 63;
  const int wm = wave & 1, wn = wave >> 1;
  const int m0 = blockIdx.y * 128, n0 = blockIdx.x * 128;

  float4v acc[4][4];
#pragma unroll
  for (int t = 0; t < 4; t++)
#pragma unroll
    for (int u = 0; u < 4; u++) acc[t][u] = (float4v){0.f, 0.f, 0.f, 0.f};

  for (int k0 = 0; k0 < K; k0 += 64) {
    __syncthreads();
#pragma unroll
    for (int i = 0; i < 4; i++) {
      const int c = i * 256 + tid;        // 0..1023
      const int row = c >> 3, ch = c & 7; // 128 rows x 8 chunks of 8 u16
      *(short8*)(As + row * 72 + ch * 8) =
          *(const short8*)(A + (size_t)(m0 + row) * K + k0 + ch * 8);
      *(short8*)(Bs + row * 72 + ch * 8) =
          *(const short8*)(Bt + (size_t)(n0 + row) * K + k0 + ch * 8);
    }
    __syncthreads();
#pragma unroll
    for (int ks = 0; ks < 2; ks++) {
      short8 af[4], bfr[4];
#pragma unroll
      for (int t = 0; t < 4; t++) {
        const int ar = wm * 64 + t * 16 + (lane & 15);
        af[t] = *(const short8*)(As + ar * 72 + (ks * 4 + (lane >> 4)) * 8);
        const int br = wn * 64 + t * 16 + (lane & 15);
        bfr[t] = *(const short8*)(Bs + br * 72 + (ks * 4 + (lane >> 4)) * 8);
      }
#pragma unroll
      for (int t = 0; t < 4; t++)
#pragma unroll
        for (int u = 0; u < 4; u++)
          acc[t][u] = __builtin_amdgcn_mfma_f32_16x16x32_bf16(af[t], bfr[u], acc[t][u], 0, 0, 0);
    }
  }

  // Epilogue. C/D layout: row=(lane>>4)*4+reg, col=lane&15.
  const int qr = (lane >> 4) << 2;
#pragma unroll
  for (int t = 0; t < 4; t++) {
    const int mrow = m0 + wm * 64 + t * 16 + qr;
#pragma unroll
    for (int u = 0; u < 4; u++) {
      const int col = n0 + wn * 64 + u * 16 + (lane & 15);
      const float bv = bias[col];
#pragma unroll
      for (int r = 0; r < 4; r++) {
        const float val = acc[t][u][r] + bv;
        if (out32) ((float*)C)[(size_t)(mrow + r) * N + col] = val;
        else       ((u16*)C)[(size_t)(mrow + r) * N + col] = f2bf(val);
      }
    }
  }
}

// ---------------------------------------------------------------------------
// Flash attention (causal), bf16 in/out, fp32 softmax state.
// qkv: [B*S][3D], q at h*64, k at D+h*64, v at 2D+h*64.
// Block: 64 Q-rows (4 waves x 16). Stream 64-key tiles up to the diagonal.
// ---------------------------------------------------------------------------
#define FA_S 2048
#define FA_D 1024
#define FA_LD 3072
#define NEG_BIG (-1e30f)

__global__ __launch_bounds__(256) void flash_kernel(
    const u16* __restrict__ qkv, const float* __restrict__ am,
    u16* __restrict__ aout) {
  __shared__ __align__(16) u16 Ks[64 * 72];     // K tile [key][hd]
  __shared__ __align__(16) u16 Vt[64 * 72];     // V^T tile [hd][key]
  __shared__ __align__(16) u16 Ps[4][16 * 72];  // per-wave P tile [qrow][key]

  const int tid = threadIdx.x, wave = tid >> 6, lane = tid & 63;
  const int qt = blockIdx.x;
  const int bh = blockIdx.y, b = bh >> 4, h = bh & 15;
  const size_t rowbase = (size_t)b * FA_S;

  short8 qf[2];
  {
    const int qrow = qt * 64 + wave * 16 + (lane & 15);
    const u16* qp = qkv + (rowbase + qrow) * FA_LD + h * 64 + ((lane >> 4) * 8);
    qf[0] = *(const short8*)qp;
    qf[1] = *(const short8*)(qp + 32);
  }

  float m_i[4], l_i[4];
  float4v o[4];
#pragma unroll
  for (int r = 0; r < 4; r++) { m_i[r] = NEG_BIG; l_i[r] = 0.f; }
#pragma unroll
  for (int u = 0; u < 4; u++) o[u] = (float4v){0.f, 0.f, 0.f, 0.f};

  const int q_row_g = qt * 64 + wave * 16 + ((lane >> 4) << 2);

  for (int kt = 0; kt <= qt; kt++) {
    __syncthreads();
#pragma unroll
    for (int i = 0; i < 2; i++) {
      const int c = i * 256 + tid;
      const int row = c >> 3, ch = c & 7;
      *(short8*)(Ks + row * 72 + ch * 8) =
          *(const short8*)(qkv + (rowbase + kt * 64 + row) * FA_LD + FA_D + h * 64 + ch * 8);
    }
    {
      const int key = tid >> 2;
      const int hd0 = (tid & 3) * 16;
      const u16* g = qkv + (rowbase + kt * 64 + key) * FA_LD + 2 * FA_D + h * 64 + hd0;
      short8 t0 = *(const short8*)g;
      short8 t1 = *(const short8*)(g + 8);
      __align__(16) u16 tmp[16];
      *(short8*)tmp = t0;
      *(short8*)(tmp + 8) = t1;
#pragma unroll
      for (int j = 0; j < 16; j++)
        Vt[(hd0 + j) * 72 + key] = tmp[j];
    }
    __syncthreads();

    float4v s[4];
#pragma unroll
    for (int nt = 0; nt < 4; nt++) s[nt] = (float4v){0.f, 0.f, 0.f, 0.f};
#pragma unroll
    for (int ks = 0; ks < 2; ks++) {
#pragma unroll
      for (int nt = 0; nt < 4; nt++) {
        const int kr = nt * 16 + (lane & 15);
        const short8 kf = *(const short8*)(Ks + kr * 72 + (ks * 4 + (lane >> 4)) * 8);
        s[nt] = __builtin_amdgcn_mfma_f32_16x16x32_bf16(qf[ks], kf, s[nt], 0, 0, 0);
      }
    }

    float p[4][4];
    float mcur[4] = {NEG_BIG, NEG_BIG, NEG_BIG, NEG_BIG};
#pragma unroll
    for (int nt = 0; nt < 4; nt++) {
      const int key_g = kt * 64 + nt * 16 + (lane & 15);
      const float amv = am[b * FA_S + key_g];
#pragma unroll
      for (int r = 0; r < 4; r++) {
        float v = (key_g <= q_row_g + r) ? s[nt][r] * 0.125f : -10000.0f;
        v += amv;
        p[nt][r] = v;
        mcur[r] = fmaxf(mcur[r], v);
      }
    }
#pragma unroll
    for (int d = 1; d < 16; d <<= 1)
#pragma unroll
      for (int r = 0; r < 4; r++) mcur[r] = fmaxf(mcur[r], __shfl_xor(mcur[r], d, 64));
    float alpha[4];
#pragma unroll
    for (int r = 0; r < 4; r++) {
      const float mn = fmaxf(m_i[r], mcur[r]);
      alpha[r] = __expf(m_i[r] - mn);
      m_i[r] = mn;
    }
    float lsum[4] = {0.f, 0.f, 0.f, 0.f};
#pragma unroll
    for (int nt = 0; nt < 4; nt++)
#pragma unroll
      for (int r = 0; r < 4; r++) {
        const float e = __expf(p[nt][r] - m_i[r]);
        p[nt][r] = e;
        lsum[r] += e;
      }
#pragma unroll
    for (int d = 1; d < 16; d <<= 1)
#pragma unroll
      for (int r = 0; r < 4; r++) lsum[r] += __shfl_xor(lsum[r], d, 64);
#pragma unroll
    for (int r = 0; r < 4; r++) l_i[r] = l_i[r] * alpha[r] + lsum[r];
#pragma unroll
    for (int u = 0; u < 4; u++)
#pragma unroll
      for (int r = 0; r < 4; r++) o[u][r] *= alpha[r];

    u16* Pw = Ps[wave];
#pragma unroll
    for (int nt = 0; nt < 4; nt++) {
      const int col = nt * 16 + (lane & 15);
#pragma unroll
      for (int r = 0; r < 4; r++) {
        const int row = ((lane >> 4) << 2) + r;
        Pw[row * 72 + col] = f2bf(p[nt][r]);
      }
    }
    __syncthreads();

#pragma unroll
    for (int ks = 0; ks < 2; ks++) {
      const int mrow = lane & 15;
      const short8 pf = *(const short8*)(Pw + mrow * 72 + (ks * 4 + (lane >> 4)) * 8);
#pragma unroll
      for (int u = 0; u < 4; u++) {
        const int n = u * 16 + (lane & 15);
        const short8 vf = *(const short8*)(Vt + n * 72 + ks * 32 + ((lane >> 4) << 3));
        o[u] = __builtin_amdgcn_mfma_f32_16x16x32_bf16(pf, vf, o[u], 0, 0, 0);
      }
    }
  }

#pragma unroll
  for (int u = 0; u < 4; u++) {
    const int col = h * 64 + u * 16 + (lane & 15);
#pragma unroll
    for (int r = 0; r < 4; r++) {
      const float val = o[u][r] / l_i[r];
      aout[(rowbase + q_row_g + r) * FA_D + col] = f2bf(val);
    }
  }
}

// ---------------------------------------------------------------------------
extern "C" void kernel_launch(void* const* d_in, const int* in_sizes, int n_in,
                              void* d_out, int out_size, void* d_ws, size_t ws_size,
                              hipStream_t stream) {
  (void)out_size; (void)ws_size;
  auto find = [&](int count, int def_idx) -> const void* {
    for (int i = 0; i < n_in; i++)
      if (in_sizes[i] == count) return d_in[i];
    return d_in[def_idx];
  };
  const void* x  = find(8388608, 0);  // (4,2048,1024) fp32
  const void* am = find(8192, 1);     // (4,1,1,2048)
  const void* Wa = find(3145728, 2);  // (1024,3072)
  const void* ba = find(3072, 3);     // (3072,)
  const void* Wp = find(1048576, 4);  // (1024,1024)
  const void* bp = find(1024, 5);     // (1024,)

  char* ws = (char*)d_ws;
  u16*   x_c  = (u16*)(ws + 0);          // 16,777,216
  u16*   Wa_t = (u16*)(ws + 16777216);   //  6,291,456
  u16*   Wp_t = (u16*)(ws + 23068672);   //  2,097,152
  u16*   qkv  = (u16*)(ws + 25165824);   // 50,331,648
  u16*   abuf = (u16*)(ws + 75497472);   // 16,777,216
  float* ba_f = (float*)(ws + 92274688); //     12,288
  float* bp_f = (float*)(ws + 92286976); //      4,096
  float* am_f = (float*)(ws + 92291072); //     32,768
  int*   flag = (int*)(ws + 92323840);   // total ~92.3 MB (validated in R3)

  const int M = 8192, D = 1024;

  detect_kernel<<<1, 256, 0, stream>>>((const u16*)x, flag);
  cvt_bf16_kernel<<<2048, 256, 0, stream>>>(x, flag, x_c, M * D);
  cvt_f32_kernel<<<12, 256, 0, stream>>>(ba, flag, ba_f, 3072);
  cvt_f32_kernel<<<4, 256, 0, stream>>>(bp, flag, bp_f, 1024);
  cvt_f32_kernel<<<32, 256, 0, stream>>>(am, flag, am_f, 4 * FA_S);
  cvt_transpose_kernel<<<dim3(3072 / 64, 1024 / 64), 256, 0, stream>>>(Wa, flag, Wa_t, 1024, 3072);
  cvt_transpose_kernel<<<dim3(1024 / 64, 1024 / 64), 256, 0, stream>>>(Wp, flag, Wp_t, 1024, 1024);

  gemm_bt_kernel<<<dim3(3072 / 128, M / 128), 256, 0, stream>>>(
      x_c, Wa_t, ba_f, qkv, M, 3072, D, 0);
  flash_kernel<<<dim3(32, 64), 256, 0, stream>>>(qkv, am_f, abuf);
  gemm_bt_kernel<<<dim3(D / 128, M / 128), 256, 0, stream>>>(
      abuf, Wp_t, bp_f, d_out, M, D, D, 1);
}

// Round 9
// 512.363 us; speedup vs baseline: 14.8695x; 1.0003x over previous
//
#include <hip/hip_runtime.h>
#include <stdint.h>
#include <stddef.h>

typedef unsigned short u16;
typedef __attribute__((ext_vector_type(8))) short short8;   // 8 x bf16 MFMA A/B frag
typedef __attribute__((ext_vector_type(4))) float float4v;  // MFMA C/D frag

typedef const __attribute__((address_space(1))) void* gas_p;
typedef __attribute__((address_space(3))) void* las_p;

__device__ __forceinline__ float bf2f(u16 h) {
  union { unsigned u; float f; } v; v.u = ((unsigned)h) << 16; return v.f;
}
__device__ __forceinline__ u16 f2bf(float f) {
  union { float f; unsigned u; } v; v.f = f;
  return (u16)((v.u + 0x7FFFu + ((v.u >> 16) & 1u)) >> 16);
}

// ---------------------------------------------------------------------------
__global__ __launch_bounds__(256) void detect_kernel(const u16* __restrict__ src,
                                                     int* __restrict__ flag) {
  __shared__ int cnt[256];
  int c = 0;
  for (int j = 0; j < 256; j++) {
    const u16 w = src[threadIdx.x + j * 256];
    c += (((w >> 7) & 0xFF) == 0xFF) ? 1 : 0;
  }
  cnt[threadIdx.x] = c;
  __syncthreads();
  if (threadIdx.x == 0) {
    int t = 0;
    for (int i = 0; i < 256; i++) t += cnt[i];
    *flag = (t > 0) ? 1 : 0;
  }
}

__global__ __launch_bounds__(256) void cvt_bf16_kernel(const void* __restrict__ src,
                                                       const int* __restrict__ flag,
                                                       u16* __restrict__ dst, int n) {
  const int f = *flag;
  const int stride = gridDim.x * 256;
  for (int i = blockIdx.x * 256 + threadIdx.x; i < n; i += stride)
    dst[i] = f ? f2bf(((const float*)src)[i]) : ((const u16*)src)[i];
}

__global__ __launch_bounds__(256) void cvt_f32_kernel(const void* __restrict__ src,
                                                      const int* __restrict__ flag,
                                                      float* __restrict__ dst, int n) {
  const int f = *flag;
  const int stride = gridDim.x * 256;
  for (int i = blockIdx.x * 256 + threadIdx.x; i < n; i += stride)
    dst[i] = f ? ((const float*)src)[i] : bf2f(((const u16*)src)[i]);
}

__global__ __launch_bounds__(256) void cvt_transpose_kernel(
    const void* __restrict__ src, const int* __restrict__ flag,
    u16* __restrict__ dst, int R, int C) {
  __shared__ u16 tile[64][65];
  const int f = *flag;
  const int c0 = blockIdx.x * 64, r0 = blockIdx.y * 64;
  const int tc = threadIdx.x & 63;
  const int tr0 = (threadIdx.x >> 6) * 16;
#pragma unroll
  for (int i = 0; i < 16; i++) {
    const size_t idx = (size_t)(r0 + tr0 + i) * C + c0 + tc;
    tile[tr0 + i][tc] = f ? f2bf(((const float*)src)[idx]) : ((const u16*)src)[idx];
  }
  __syncthreads();
#pragma unroll
  for (int i = 0; i < 16; i++)
    dst[(size_t)(c0 + tr0 + i) * R + r0 + tc] = tile[tc][tr0 + i];
}

// ---------------------------------------------------------------------------
// C[M][N] = A[M][K] @ Bt[N][K]^T + bias[N]  (bf16 in, fp32 accum)
// m97-proven structure: 128x128 tile, BK=64, global_load_lds width-16,
// LDS stride 64 u16 (no pad — required by the wave-uniform-dest contract).
// ---------------------------------------------------------------------------
__global__ __launch_bounds__(256) void gemm_bt_kernel(
    const u16* __restrict__ A, const u16* __restrict__ Bt,
    const float* __restrict__ bias, void* __restrict__ C,
    int M, int N, int K, int out32) {
  __shared__ u16 As[128 * 64];
  __shared__ u16 Bs[128 * 64];
  const int tid = threadIdx.x;
  const int wave = tid >> 6, lane = tid & 63;
  const int wm = wave & 1, wn = wave >> 1;
  const int m0 = blockIdx.y * 128, n0 = blockIdx.x * 128;
  const int lr = lane >> 3, lc = lane & 7;

  float4v acc[4][4];
#pragma unroll
  for (int t = 0; t < 4; t++)
#pragma unroll
    for (int u = 0; u < 4; u++) acc[t][u] = (float4v){0.f, 0.f, 0.f, 0.f};

  for (int k0 = 0; k0 < K; k0 += 64) {
    __syncthreads();
#pragma unroll
    for (int i = 0; i < 4; i++) {
      const int brow = wave * 32 + i * 8;
      const int row = brow + lr;
      __builtin_amdgcn_global_load_lds(
          (gas_p)(A + (size_t)(m0 + row) * K + k0 + lc * 8),
          (las_p)(As + brow * 64), 16, 0, 0);
      __builtin_amdgcn_global_load_lds(
          (gas_p)(Bt + (size_t)(n0 + row) * K + k0 + lc * 8),
          (las_p)(Bs + brow * 64), 16, 0, 0);
    }
    __syncthreads();
#pragma unroll
    for (int ks = 0; ks < 2; ks++) {
      short8 af[4], bfr[4];
#pragma unroll
      for (int t = 0; t < 4; t++) {
        const int ar = wm * 64 + t * 16 + (lane & 15);
        af[t] = *(const short8*)(As + ar * 64 + (ks * 4 + (lane >> 4)) * 8);
        const int br = wn * 64 + t * 16 + (lane & 15);
        bfr[t] = *(const short8*)(Bs + br * 64 + (ks * 4 + (lane >> 4)) * 8);
      }
#pragma unroll
      for (int t = 0; t < 4; t++)
#pragma unroll
        for (int u = 0; u < 4; u++)
          acc[t][u] = __builtin_amdgcn_mfma_f32_16x16x32_bf16(af[t], bfr[u], acc[t][u], 0, 0, 0);
    }
  }

  const int qr = (lane >> 4) << 2;
#pragma unroll
  for (int t = 0; t < 4; t++) {
    const int mrow = m0 + wm * 64 + t * 16 + qr;
#pragma unroll
    for (int u = 0; u < 4; u++) {
      const int col = n0 + wn * 64 + u * 16 + (lane & 15);
      const float bv = bias[col];
#pragma unroll
      for (int r = 0; r < 4; r++) {
        const float val = acc[t][u][r] + bv;
        if (out32) ((float*)C)[(size_t)(mrow + r) * N + col] = val;
        else       ((u16*)C)[(size_t)(mrow + r) * N + col] = f2bf(val);
      }
    }
  }
}

// ---------------------------------------------------------------------------
// Flash attention (causal). Q-tile 128 rows/block (4 waves x 32 rows),
// 64-key tiles. K via global_load_lds (stride 64); V^T with bank-offset rows.
// ---------------------------------------------------------------------------
#define FA_S 2048
#define FA_D 1024
#define FA_LD 3072
#define NEG_BIG (-1e30f)

__global__ __launch_bounds__(256) void flash_kernel(
    const u16* __restrict__ qkv, const float* __restrict__ am,
    u16* __restrict__ aout) {
  __shared__ u16 Ks[64 * 64];              // [key][hd], stride 64
  __shared__ u16 Vt[64 * 72 + 32];         // [hd][key], row off +(row>>4)*8
  __shared__ u16 Ps[4][32 * 72];           // per-wave P [qrow][key]

  const int tid = threadIdx.x, wave = tid >> 6, lane = tid & 63;
  const int qt = 15 - blockIdx.x;          // longest-first
  const int bh = blockIdx.y, b = bh >> 4, h = bh & 15;
  const size_t rowbase = (size_t)b * FA_S;
  const int quad = lane >> 4, l15 = lane & 15;

  // Q fragments: 2 m-subtiles x 2 k-halves
  short8 qf[2][2];
#pragma unroll
  for (int m = 0; m < 2; m++) {
    const int qrow = qt * 128 + wave * 32 + m * 16 + l15;
    const u16* qp = qkv + (rowbase + qrow) * FA_LD + h * 64 + quad * 8;
    qf[m][0] = *(const short8*)qp;
    qf[m][1] = *(const short8*)(qp + 32);
  }

  float m_i[2][4], l_i[2][4];
  float4v o[2][4];
#pragma unroll
  for (int m = 0; m < 2; m++)
#pragma unroll
    for (int r = 0; r < 4; r++) { m_i[m][r] = NEG_BIG; l_i[m][r] = 0.f; }
#pragma unroll
  for (int m = 0; m < 2; m++)
#pragma unroll
    for (int u = 0; u < 4; u++) o[m][u] = (float4v){0.f, 0.f, 0.f, 0.f};

  const int qrg0 = qt * 128 + wave * 32 + quad * 4;  // + m*16 + r

  const int kt_end = 2 * qt + 1;
  for (int kt = 0; kt <= kt_end; kt++) {
    __syncthreads();
    // K tile: 8 global_load_lds (2/wave)
#pragma unroll
    for (int i = 0; i < 2; i++) {
      const int brow = wave * 16 + i * 8;
      const int row = brow + (lane >> 3);
      __builtin_amdgcn_global_load_lds(
          (gas_p)(qkv + (rowbase + kt * 64 + row) * FA_LD + FA_D + h * 64 + (lane & 7) * 8),
          (las_p)(Ks + brow * 64), 16, 0, 0);
    }
    // V transposed: thread reads 16 hd of one key
    {
      const int key = tid >> 2;
      const int hd0 = (tid & 3) * 16;
      const u16* g = qkv + (rowbase + kt * 64 + key) * FA_LD + 2 * FA_D + h * 64 + hd0;
      short8 t0 = *(const short8*)g;
      short8 t1 = *(const short8*)(g + 8);
      __align__(16) u16 tmp[16];
      *(short8*)tmp = t0;
      *(short8*)(tmp + 8) = t1;
#pragma unroll
      for (int j = 0; j < 16; j++) {
        const int row = hd0 + j;
        Vt[row * 72 + ((row >> 4) << 3) + key] = tmp[j];
      }
    }
    __syncthreads();

    // S = Q K^T
    float4v s[2][4];
#pragma unroll
    for (int m = 0; m < 2; m++)
#pragma unroll
      for (int nt = 0; nt < 4; nt++) s[m][nt] = (float4v){0.f, 0.f, 0.f, 0.f};
#pragma unroll
    for (int ks = 0; ks < 2; ks++) {
#pragma unroll
      for (int nt = 0; nt < 4; nt++) {
        const int kr = nt * 16 + l15;
        const short8 kf = *(const short8*)(Ks + kr * 64 + (ks * 4 + quad) * 8);
#pragma unroll
        for (int m = 0; m < 2; m++)
          s[m][nt] = __builtin_amdgcn_mfma_f32_16x16x32_bf16(qf[m][ks], kf, s[m][nt], 0, 0, 0);
      }
    }

    // scale + causal mask + mask add; online softmax (reuse s as P)
    float mcur[2][4];
#pragma unroll
    for (int m = 0; m < 2; m++)
#pragma unroll
      for (int r = 0; r < 4; r++) mcur[m][r] = NEG_BIG;
#pragma unroll
    for (int nt = 0; nt < 4; nt++) {
      const int key_g = kt * 64 + nt * 16 + l15;
      const float amv = am[b * FA_S + key_g];
#pragma unroll
      for (int m = 0; m < 2; m++) {
        const int qr0 = qrg0 + m * 16;
#pragma unroll
        for (int r = 0; r < 4; r++) {
          float v = (key_g <= qr0 + r) ? s[m][nt][r] * 0.125f : -10000.0f;
          v += amv;
          s[m][nt][r] = v;
          mcur[m][r] = fmaxf(mcur[m][r], v);
        }
      }
    }
#pragma unroll
    for (int d = 1; d < 16; d <<= 1)
#pragma unroll
      for (int m = 0; m < 2; m++)
#pragma unroll
        for (int r = 0; r < 4; r++)
          mcur[m][r] = fmaxf(mcur[m][r], __shfl_xor(mcur[m][r], d, 64));
    float alpha[2][4];
#pragma unroll
    for (int m = 0; m < 2; m++)
#pragma unroll
      for (int r = 0; r < 4; r++) {
        const float mn = fmaxf(m_i[m][r], mcur[m][r]);
        alpha[m][r] = __expf(m_i[m][r] - mn);
        m_i[m][r] = mn;
      }
    float lsum[2][4] = {};
#pragma unroll
    for (int m = 0; m < 2; m++)
#pragma unroll
      for (int nt = 0; nt < 4; nt++)
#pragma unroll
        for (int r = 0; r < 4; r++) {
          const float e = __expf(s[m][nt][r] - m_i[m][r]);
          s[m][nt][r] = e;
          lsum[m][r] += e;
        }
#pragma unroll
    for (int d = 1; d < 16; d <<= 1)
#pragma unroll
      for (int m = 0; m < 2; m++)
#pragma unroll
        for (int r = 0; r < 4; r++) lsum[m][r] += __shfl_xor(lsum[m][r], d, 64);
#pragma unroll
    for (int m = 0; m < 2; m++)
#pragma unroll
      for (int r = 0; r < 4; r++) l_i[m][r] = l_i[m][r] * alpha[m][r] + lsum[m][r];
#pragma unroll
    for (int m = 0; m < 2; m++)
#pragma unroll
      for (int u = 0; u < 4; u++)
#pragma unroll
        for (int r = 0; r < 4; r++) o[m][u][r] *= alpha[m][r];

    // P -> LDS (A-operand layout transform)
    u16* Pw = Ps[wave];
#pragma unroll
    for (int m = 0; m < 2; m++)
#pragma unroll
      for (int nt = 0; nt < 4; nt++) {
        const int col = nt * 16 + l15;
#pragma unroll
        for (int r = 0; r < 4; r++)
          Pw[(m * 16 + quad * 4 + r) * 72 + col] = f2bf(s[m][nt][r]);
      }
    __syncthreads();

    // O += P V
#pragma unroll
    for (int ks = 0; ks < 2; ks++) {
#pragma unroll
      for (int m = 0; m < 2; m++) {
        const short8 pf = *(const short8*)(Pw + (m * 16 + l15) * 72 + (ks * 4 + quad) * 8);
#pragma unroll
        for (int u = 0; u < 4; u++) {
          const int n = u * 16 + l15;
          const short8 vf = *(const short8*)(Vt + n * 72 + ((n >> 4) << 3) + ks * 32 + quad * 8);
          o[m][u] = __builtin_amdgcn_mfma_f32_16x16x32_bf16(pf, vf, o[m][u], 0, 0, 0);
        }
      }
    }
  }

  // normalize + write merged heads
#pragma unroll
  for (int m = 0; m < 2; m++)
#pragma unroll
    for (int u = 0; u < 4; u++) {
      const int col = h * 64 + u * 16 + l15;
#pragma unroll
      for (int r = 0; r < 4; r++) {
        const float val = o[m][u][r] / l_i[m][r];
        aout[(rowbase + qrg0 + m * 16 + r) * FA_D + col] = f2bf(val);
      }
    }
}

// ---------------------------------------------------------------------------
extern "C" void kernel_launch(void* const* d_in, const int* in_sizes, int n_in,
                              void* d_out, int out_size, void* d_ws, size_t ws_size,
                              hipStream_t stream) {
  (void)out_size; (void)ws_size;
  auto find = [&](int count, int def_idx) -> const void* {
    for (int i = 0; i < n_in; i++)
      if (in_sizes[i] == count) return d_in[i];
    return d_in[def_idx];
  };
  const void* x  = find(8388608, 0);
  const void* am = find(8192, 1);
  const void* Wa = find(3145728, 2);
  const void* ba = find(3072, 3);
  const void* Wp = find(1048576, 4);
  const void* bp = find(1024, 5);

  char* ws = (char*)d_ws;
  u16*   x_c  = (u16*)(ws + 0);
  u16*   Wa_t = (u16*)(ws + 16777216);
  u16*   Wp_t = (u16*)(ws + 23068672);
  u16*   qkv  = (u16*)(ws + 25165824);
  u16*   abuf = (u16*)(ws + 75497472);
  float* ba_f = (float*)(ws + 92274688);
  float* bp_f = (float*)(ws + 92286976);
  float* am_f = (float*)(ws + 92291072);
  int*   flag = (int*)(ws + 92323840);

  const int M = 8192, D = 1024;

  detect_kernel<<<1, 256, 0, stream>>>((const u16*)x, flag);
  cvt_bf16_kernel<<<2048, 256, 0, stream>>>(x, flag, x_c, M * D);
  cvt_f32_kernel<<<12, 256, 0, stream>>>(ba, flag, ba_f, 3072);
  cvt_f32_kernel<<<4, 256, 0, stream>>>(bp, flag, bp_f, 1024);
  cvt_f32_kernel<<<32, 256, 0, stream>>>(am, flag, am_f, 4 * FA_S);
  cvt_transpose_kernel<<<dim3(3072 / 64, 1024 / 64), 256, 0, stream>>>(Wa, flag, Wa_t, 1024, 3072);
  cvt_transpose_kernel<<<dim3(1024 / 64, 1024 / 64), 256, 0, stream>>>(Wp, flag, Wp_t, 1024, 1024);

  gemm_bt_kernel<<<dim3(3072 / 128, M / 128), 256, 0, stream>>>(
      x_c, Wa_t, ba_f, qkv, M, 3072, D, 0);
  flash_kernel<<<dim3(16, 64), 256, 0, stream>>>(qkv, am_f, abuf);
  gemm_bt_kernel<<<dim3(D / 128, M / 128), 256, 0, stream>>>(
      abuf, Wp_t, bp_f, d_out, M, D, D, 1);
}

// Round 10
// 417.845 us; speedup vs baseline: 18.2330x; 1.2262x over previous
//
#include <hip/hip_runtime.h>
#include <stdint.h>
#include <stddef.h>

typedef unsigned short u16;
typedef __attribute__((ext_vector_type(8))) short short8;   // 8 x bf16 MFMA A/B frag
typedef __attribute__((ext_vector_type(4))) float float4v;  // MFMA C/D frag

typedef const __attribute__((address_space(1))) void* gas_p;
typedef __attribute__((address_space(3))) void* las_p;

__device__ __forceinline__ float bf2f(u16 h) {
  union { unsigned u; float f; } v; v.u = ((unsigned)h) << 16; return v.f;
}
__device__ __forceinline__ u16 f2bf(float f) {
  union { float f; unsigned u; } v; v.f = f;
  return (u16)((v.u + 0x7FFFu + ((v.u >> 16) & 1u)) >> 16);
}

// ---------------------------------------------------------------------------
__global__ __launch_bounds__(256) void detect_kernel(const u16* __restrict__ src,
                                                     int* __restrict__ flag) {
  __shared__ int cnt[256];
  int c = 0;
  for (int j = 0; j < 256; j++) {
    const u16 w = src[threadIdx.x + j * 256];
    c += (((w >> 7) & 0xFF) == 0xFF) ? 1 : 0;
  }
  cnt[threadIdx.x] = c;
  __syncthreads();
  if (threadIdx.x == 0) {
    int t = 0;
    for (int i = 0; i < 256; i++) t += cnt[i];
    *flag = (t > 0) ? 1 : 0;
  }
}

__global__ __launch_bounds__(256) void cvt_bf16_kernel(const void* __restrict__ src,
                                                       const int* __restrict__ flag,
                                                       u16* __restrict__ dst, int n) {
  const int f = *flag;
  const int stride = gridDim.x * 256;
  for (int i = blockIdx.x * 256 + threadIdx.x; i < n; i += stride)
    dst[i] = f ? f2bf(((const float*)src)[i]) : ((const u16*)src)[i];
}

__global__ __launch_bounds__(256) void cvt_f32_kernel(const void* __restrict__ src,
                                                      const int* __restrict__ flag,
                                                      float* __restrict__ dst, int n) {
  const int f = *flag;
  const int stride = gridDim.x * 256;
  for (int i = blockIdx.x * 256 + threadIdx.x; i < n; i += stride)
    dst[i] = f ? ((const float*)src)[i] : bf2f(((const u16*)src)[i]);
}

__global__ __launch_bounds__(256) void cvt_transpose_kernel(
    const void* __restrict__ src, const int* __restrict__ flag,
    u16* __restrict__ dst, int R, int C) {
  __shared__ u16 tile[64][65];
  const int f = *flag;
  const int c0 = blockIdx.x * 64, r0 = blockIdx.y * 64;
  const int tc = threadIdx.x & 63;
  const int tr0 = (threadIdx.x >> 6) * 16;
#pragma unroll
  for (int i = 0; i < 16; i++) {
    const size_t idx = (size_t)(r0 + tr0 + i) * C + c0 + tc;
    tile[tr0 + i][tc] = f ? f2bf(((const float*)src)[idx]) : ((const u16*)src)[idx];
  }
  __syncthreads();
#pragma unroll
  for (int i = 0; i < 16; i++)
    dst[(size_t)(c0 + tr0 + i) * R + r0 + tc] = tile[tc][tr0 + i];
}

// ---------------------------------------------------------------------------
// C[M][N] = A[M][K] @ Bt[N][K]^T + bias[N]  (bf16 in, fp32 accum)
// m97 structure + XOR chunk swizzle on the GLOBAL fetch address:
// LDS[row][slot] = G[row][slot ^ (row&7)]  -> fragment reads conflict-free.
// ---------------------------------------------------------------------------
__global__ __launch_bounds__(256) void gemm_bt_kernel(
    const u16* __restrict__ A, const u16* __restrict__ Bt,
    const float* __restrict__ bias, void* __restrict__ C,
    int M, int N, int K, int out32) {
  __shared__ u16 As[128 * 64];
  __shared__ u16 Bs[128 * 64];
  const int tid = threadIdx.x;
  const int wave = tid >> 6, lane = tid & 63;
  const int wm = wave & 1, wn = wave >> 1;
  const int m0 = blockIdx.y * 128, n0 = blockIdx.x * 128;
  const int lr = lane >> 3, lc = lane & 7;
  const int quad = lane >> 4, l15 = lane & 15;

  float4v acc[4][4];
#pragma unroll
  for (int t = 0; t < 4; t++)
#pragma unroll
    for (int u = 0; u < 4; u++) acc[t][u] = (float4v){0.f, 0.f, 0.f, 0.f};

  for (int k0 = 0; k0 < K; k0 += 64) {
    __syncthreads();
#pragma unroll
    for (int i = 0; i < 4; i++) {
      const int brow = wave * 32 + i * 8;
      const int row = brow + lr;
      const int cG = lc ^ (row & 7);
      __builtin_amdgcn_global_load_lds(
          (gas_p)(A + (size_t)(m0 + row) * K + k0 + cG * 8),
          (las_p)(As + brow * 64), 16, 0, 0);
      __builtin_amdgcn_global_load_lds(
          (gas_p)(Bt + (size_t)(n0 + row) * K + k0 + cG * 8),
          (las_p)(Bs + brow * 64), 16, 0, 0);
    }
    __syncthreads();
#pragma unroll
    for (int ks = 0; ks < 2; ks++) {
      short8 af[4], bfr[4];
#pragma unroll
      for (int t = 0; t < 4; t++) {
        const int ar = wm * 64 + t * 16 + l15;
        af[t] = *(const short8*)(As + ar * 64 + ((ks * 4 + quad) ^ (ar & 7)) * 8);
        const int br = wn * 64 + t * 16 + l15;
        bfr[t] = *(const short8*)(Bs + br * 64 + ((ks * 4 + quad) ^ (br & 7)) * 8);
      }
#pragma unroll
      for (int t = 0; t < 4; t++)
#pragma unroll
        for (int u = 0; u < 4; u++)
          acc[t][u] = __builtin_amdgcn_mfma_f32_16x16x32_bf16(af[t], bfr[u], acc[t][u], 0, 0, 0);
    }
  }

  const int qr = quad << 2;
#pragma unroll
  for (int t = 0; t < 4; t++) {
    const int mrow = m0 + wm * 64 + t * 16 + qr;
#pragma unroll
    for (int u = 0; u < 4; u++) {
      const int col = n0 + wn * 64 + u * 16 + l15;
      const float bv = bias[col];
#pragma unroll
      for (int r = 0; r < 4; r++) {
        const float val = acc[t][u][r] + bv;
        if (out32) ((float*)C)[(size_t)(mrow + r) * N + col] = val;
        else       ((u16*)C)[(size_t)(mrow + r) * N + col] = f2bf(val);
      }
    }
  }
}

// ---------------------------------------------------------------------------
// Flash attention (causal). 64-row Q-tiles; each block processes the
// complementary pair (qt, 31-qt) -> exactly 33 K-iterations per block
// (perfect balance, sustained occupancy). K staged via swizzled
// global_load_lds; V^T with 16-u16 group offset; P->PV intra-wave (no
// barrier). Q pre-scaled by 0.125 (exact). Diagonal-only causal compare.
// ---------------------------------------------------------------------------
#define FA_S 2048
#define FA_D 1024
#define FA_LD 3072
#define NEG_BIG (-1e30f)

__global__ __launch_bounds__(256) void flash_kernel(
    const u16* __restrict__ qkv, const float* __restrict__ am,
    u16* __restrict__ aout) {
  __shared__ u16 Ks[64 * 64];          // [key][slot], slot = chunk^(key&7)
  __shared__ u16 Vt[64 * 72 + 64];     // [hd][key] + ((hd>>4)<<4) offset
  __shared__ u16 Ps[4][16 * 72];       // per-wave P [qrow][key]

  const int tid = threadIdx.x, wave = tid >> 6, lane = tid & 63;
  const int qp = blockIdx.x;           // 0..15 -> tiles {qp, 31-qp}
  const int bh = blockIdx.y, b = bh >> 4, h = bh & 15;
  const size_t rowbase = (size_t)b * FA_S;
  const int quad = lane >> 4, l15 = lane & 15;
  const float* amrow0 = am + b * FA_S;

  for (int ph = 0; ph < 2; ph++) {
    const int qt = ph ? (31 - qp) : qp;

    // Q fragments, pre-scaled by 1/8 (exact power of 2)
    short8 qf[2];
    {
      const int qrow = qt * 64 + wave * 16 + l15;
      const u16* qp_ = qkv + (rowbase + qrow) * FA_LD + h * 64 + quad * 8;
      __align__(16) u16 t0[8], t1[8];
      *(short8*)t0 = *(const short8*)qp_;
      *(short8*)t1 = *(const short8*)(qp_ + 32);
#pragma unroll
      for (int j = 0; j < 8; j++) {
        t0[j] = f2bf(bf2f(t0[j]) * 0.125f);
        t1[j] = f2bf(bf2f(t1[j]) * 0.125f);
      }
      qf[0] = *(const short8*)t0;
      qf[1] = *(const short8*)t1;
    }

    float m_i[4], l_i[4];
    float4v o[4];
#pragma unroll
    for (int r = 0; r < 4; r++) { m_i[r] = NEG_BIG; l_i[r] = 0.f; }
#pragma unroll
    for (int u = 0; u < 4; u++) o[u] = (float4v){0.f, 0.f, 0.f, 0.f};
    const int qrg = qt * 64 + wave * 16 + quad * 4;

    for (int kt = 0; kt <= qt; kt++) {
      __syncthreads();  // all waves done reading Ks/Vt (prev iter / prev phase)
      // --- K tile, swizzled global_load_lds ---
#pragma unroll
      for (int i = 0; i < 2; i++) {
        const int brow = wave * 16 + i * 8;
        const int row = brow + (lane >> 3);
        const int cG = (lane & 7) ^ (row & 7);
        __builtin_amdgcn_global_load_lds(
            (gas_p)(qkv + (rowbase + kt * 64 + row) * FA_LD + FA_D + h * 64 + cG * 8),
            (las_p)(Ks + brow * 64), 16, 0, 0);
      }
      // --- V transposed ---
      {
        const int key = tid >> 2;
        const int hd0 = (tid & 3) * 16;
        const u16* g = qkv + (rowbase + kt * 64 + key) * FA_LD + 2 * FA_D + h * 64 + hd0;
        short8 v0 = *(const short8*)g;
        short8 v1 = *(const short8*)(g + 8);
        __align__(16) u16 tmp[16];
        *(short8*)tmp = v0;
        *(short8*)(tmp + 8) = v1;
#pragma unroll
        for (int j = 0; j < 16; j++) {
          const int row = hd0 + j;
          Vt[row * 72 + ((row >> 4) << 4) + key] = tmp[j];
        }
      }
      __syncthreads();

      // --- S = Q K^T ---
      float4v s[4];
#pragma unroll
      for (int nt = 0; nt < 4; nt++) s[nt] = (float4v){0.f, 0.f, 0.f, 0.f};
#pragma unroll
      for (int ks = 0; ks < 2; ks++) {
#pragma unroll
        for (int nt = 0; nt < 4; nt++) {
          const int kr = nt * 16 + l15;
          const short8 kf = *(const short8*)(Ks + kr * 64 + (((ks * 4 + quad) ^ (kr & 7)) << 3));
          s[nt] = __builtin_amdgcn_mfma_f32_16x16x32_bf16(qf[ks], kf, s[nt], 0, 0, 0);
        }
      }

      // --- mask + online softmax ---
      float mcur[4] = {NEG_BIG, NEG_BIG, NEG_BIG, NEG_BIG};
      const float* amrow = amrow0 + kt * 64;
      if (kt == qt) {  // diagonal tile: causal compare needed
#pragma unroll
        for (int nt = 0; nt < 4; nt++) {
          const int key_l = nt * 16 + l15;
          const float amv = amrow[key_l];
          const int key_g = kt * 64 + key_l;
#pragma unroll
          for (int r = 0; r < 4; r++) {
            float v = (key_g <= qrg + r) ? s[nt][r] : -10000.0f;
            v += amv;
            s[nt][r] = v;
            mcur[r] = fmaxf(mcur[r], v);
          }
        }
      } else {
#pragma unroll
        for (int nt = 0; nt < 4; nt++) {
          const float amv = amrow[nt * 16 + l15];
#pragma unroll
          for (int r = 0; r < 4; r++) {
            const float v = s[nt][r] + amv;
            s[nt][r] = v;
            mcur[r] = fmaxf(mcur[r], v);
          }
        }
      }
#pragma unroll
      for (int d = 1; d < 16; d <<= 1)
#pragma unroll
        for (int r = 0; r < 4; r++) mcur[r] = fmaxf(mcur[r], __shfl_xor(mcur[r], d, 64));
      float alpha[4];
#pragma unroll
      for (int r = 0; r < 4; r++) {
        const float mn = fmaxf(m_i[r], mcur[r]);
        alpha[r] = __expf(m_i[r] - mn);
        m_i[r] = mn;
      }
      float lsum[4] = {0.f, 0.f, 0.f, 0.f};
#pragma unroll
      for (int nt = 0; nt < 4; nt++)
#pragma unroll
        for (int r = 0; r < 4; r++) {
          const float e = __expf(s[nt][r] - m_i[r]);
          s[nt][r] = e;
          lsum[r] += e;
        }
#pragma unroll
      for (int d = 1; d < 16; d <<= 1)
#pragma unroll
        for (int r = 0; r < 4; r++) lsum[r] += __shfl_xor(lsum[r], d, 64);
#pragma unroll
      for (int r = 0; r < 4; r++) l_i[r] = l_i[r] * alpha[r] + lsum[r];
#pragma unroll
      for (int u = 0; u < 4; u++)
#pragma unroll
        for (int r = 0; r < 4; r++) o[u][r] *= alpha[r];

      // --- P -> own-wave LDS (intra-wave: DS program order, no barrier) ---
      u16* Pw = Ps[wave];
#pragma unroll
      for (int nt = 0; nt < 4; nt++) {
        const int col = nt * 16 + l15;
#pragma unroll
        for (int r = 0; r < 4; r++)
          Pw[(quad * 4 + r) * 72 + col] = f2bf(s[nt][r]);
      }

      // --- O += P V ---
#pragma unroll
      for (int ks = 0; ks < 2; ks++) {
        const short8 pf = *(const short8*)(Pw + l15 * 72 + (ks * 4 + quad) * 8);
#pragma unroll
        for (int u = 0; u < 4; u++) {
          const int n = u * 16 + l15;
          const short8 vf = *(const short8*)(Vt + n * 72 + ((n >> 4) << 4) + ks * 32 + quad * 8);
          o[u] = __builtin_amdgcn_mfma_f32_16x16x32_bf16(pf, vf, o[u], 0, 0, 0);
        }
      }
    }

    // --- epilogue for this Q-tile (registers + global only) ---
#pragma unroll
    for (int u = 0; u < 4; u++) {
      const int col = h * 64 + u * 16 + l15;
#pragma unroll
      for (int r = 0; r < 4; r++) {
        const float val = o[u][r] / l_i[r];
        aout[(rowbase + qrg + r) * FA_D + col] = f2bf(val);
      }
    }
  }
}

// ---------------------------------------------------------------------------
extern "C" void kernel_launch(void* const* d_in, const int* in_sizes, int n_in,
                              void* d_out, int out_size, void* d_ws, size_t ws_size,
                              hipStream_t stream) {
  (void)out_size; (void)ws_size;
  auto find = [&](int count, int def_idx) -> const void* {
    for (int i = 0; i < n_in; i++)
      if (in_sizes[i] == count) return d_in[i];
    return d_in[def_idx];
  };
  const void* x  = find(8388608, 0);
  const void* am = find(8192, 1);
  const void* Wa = find(3145728, 2);
  const void* ba = find(3072, 3);
  const void* Wp = find(1048576, 4);
  const void* bp = find(1024, 5);

  char* ws = (char*)d_ws;
  u16*   x_c  = (u16*)(ws + 0);
  u16*   Wa_t = (u16*)(ws + 16777216);
  u16*   Wp_t = (u16*)(ws + 23068672);
  u16*   qkv  = (u16*)(ws + 25165824);
  u16*   abuf = (u16*)(ws + 75497472);
  float* ba_f = (float*)(ws + 92274688);
  float* bp_f = (float*)(ws + 92286976);
  float* am_f = (float*)(ws + 92291072);
  int*   flag = (int*)(ws + 92323840);

  const int M = 8192, D = 1024;

  detect_kernel<<<1, 256, 0, stream>>>((const u16*)x, flag);
  cvt_bf16_kernel<<<2048, 256, 0, stream>>>(x, flag, x_c, M * D);
  cvt_f32_kernel<<<12, 256, 0, stream>>>(ba, flag, ba_f, 3072);
  cvt_f32_kernel<<<4, 256, 0, stream>>>(bp, flag, bp_f, 1024);
  cvt_f32_kernel<<<32, 256, 0, stream>>>(am, flag, am_f, 4 * FA_S);
  cvt_transpose_kernel<<<dim3(3072 / 64, 1024 / 64), 256, 0, stream>>>(Wa, flag, Wa_t, 1024, 3072);
  cvt_transpose_kernel<<<dim3(1024 / 64, 1024 / 64), 256, 0, stream>>>(Wp, flag, Wp_t, 1024, 1024);

  gemm_bt_kernel<<<dim3(3072 / 128, M / 128), 256, 0, stream>>>(
      x_c, Wa_t, ba_f, qkv, M, 3072, D, 0);
  flash_kernel<<<dim3(16, 64), 256, 0, stream>>>(qkv, am_f, abuf);
  gemm_bt_kernel<<<dim3(D / 128, M / 128), 256, 0, stream>>>(
      abuf, Wp_t, bp_f, d_out, M, D, D, 1);
}